// Round 8
// baseline (154.448 us; speedup 1.0000x reference)
//
#include <hip/hip_runtime.h>
#include <hip/hip_bf16.h>
#include <math.h>

// Problem constants
#define NB 131072
#define NC 128
#define NE 128
__device__ constexpr float S_    = 100.0f;
__device__ constexpr float COSM_ = 0.5403023058681398f;   // cos(1)
__device__ constexpr float SINM_ = 0.8414709848078965f;   // sin(1)
__device__ constexpr float TH_   = -0.5403023058681398f;  // cos(pi-1)
__device__ constexpr float MM_   = 0.8414709848078965f;   // sin(pi-1)*1
__device__ constexpr float C0_   = 25.0f;                 // fixed logsumexp stabilizer

using short8 = __attribute__((ext_vector_type(8))) short;
using f32x4  = __attribute__((ext_vector_type(4))) float;

// fp32 -> bf16 (RNE) on raw bits (kernel 1)
__device__ __forceinline__ unsigned int bf1(float f) {
    unsigned int u = __float_as_uint(f);
    return (u + 0x7FFFu + ((u >> 16) & 1u)) >> 16;
}
// packed fp32x2 -> bf16x2 (v_cvt_pk_bf16_f32)
__device__ __forceinline__ unsigned int pk2(float a, float b) {
    __hip_bfloat162 h = __float22bfloat162_rn(make_float2(a, b));
    union { __hip_bfloat162 h; unsigned int u; } cv; cv.h = h; return cv.u;
}

// Kernel 1: normalize weight rows -> bf16 packed in ws; zero d_out.
__global__ void wnorm_kernel(const float* __restrict__ w,
                             unsigned int* __restrict__ wn,
                             float* __restrict__ out) {
    const int row = blockIdx.x;      // 128 rows
    const int lane = threadIdx.x;    // 64 lanes
    float2 v = ((const float2*)w)[row * 64 + lane];
    float ss = v.x * v.x + v.y * v.y;
    #pragma unroll
    for (int m = 1; m < 64; m <<= 1) ss += __shfl_xor(ss, m, 64);
    float sc = 1.0f / fmaxf(sqrtf(ss), 1e-12f);
    wn[row * 64 + lane] = bf1(v.x * sc) | (bf1(v.y * sc) << 16);
    if (row == 0 && lane == 0) *out = 0.0f;
}

// Kernel 2: fused cosine GEMM + arc-margin + NLL.
// 64 rows/block (16/wave), grid 2048: 8 short block-generations per CU keep the
// memory pipe full (R7 post-mortem: one long generation starved it after t0 burst).
__global__ __launch_bounds__(256, 4)
void arcloss_kernel(const float* __restrict__ predict,
                    const float* __restrict__ target,
                    const unsigned short* __restrict__ wns,
                    float* __restrict__ out) {
    constexpr int PITCH = 132;  // ushorts/row (264 B): writes 2-way (free), reads conflict-free
    __shared__ __align__(16) unsigned short sw[128 * PITCH];
    __shared__ float swsum[4];

    const int t    = threadIdx.x;
    const int lane = t & 63;
    const int wv   = t >> 6;
    const int l15  = lane & 15;
    const int quad = lane >> 4;
    const long rowbase = (long)blockIdx.x * 64 + wv * 16;  // this wave's 16 rows

    // ---- (1) wn staging loads first (oldest in vmcnt order) ----
    const int srow = t >> 1, shalf = t & 1;
    uint4 wbuf[8];
    {
        const uint4* wsrc = (const uint4*)(wns + srow * 128 + shalf * 64);
        #pragma unroll
        for (int j = 0; j < 8; ++j) wbuf[j] = wsrc[j];
    }

    // ---- (2) predict loads: row rowbase+l15, cols quad*8 + kc*32 + {0,4} ----
    float4 praw[8];
    {
        const float* prow = predict + (rowbase + l15) * NE + quad * 8;
        #pragma unroll
        for (int kc = 0; kc < 4; ++kc) {
            praw[kc * 2]     = *(const float4*)(prow + kc * 32);
            praw[kc * 2 + 1] = *(const float4*)(prow + kc * 32 + 4);
        }
    }

    // ---- (3) target loads: row rowbase+l15, quarter quad*32..+31 ----
    float4 traw[8];
    {
        const float4* trow = (const float4*)(target + (rowbase + l15) * NC + quad * 32);
        #pragma unroll
        for (int i = 0; i < 8; ++i) traw[i] = trow[i];
    }

    // ---- (4) wn -> LDS (waits only the oldest 8 loads) ----
    {
        uint4* dst = (uint4*)(sw + srow * PITCH + shalf * 64);
        #pragma unroll
        for (int j = 0; j < 8; ++j) dst[j] = wbuf[j];
    }

    // ---- (5) predict: convert to A-frags + sumsq (norm deferred to epilogue) ----
    short8 af[4];
    float sc;
    {
        float ss = 0.f;
        #pragma unroll
        for (int kc = 0; kc < 4; ++kc) {
            float4 p0 = praw[kc * 2], p1 = praw[kc * 2 + 1];
            ss += p0.x * p0.x + p0.y * p0.y + p0.z * p0.z + p0.w * p0.w;
            ss += p1.x * p1.x + p1.y * p1.y + p1.z * p1.z + p1.w * p1.w;
            union { short8 s8; unsigned int u[4]; } uu;
            uu.u[0] = pk2(p0.x, p0.y);
            uu.u[1] = pk2(p0.z, p0.w);
            uu.u[2] = pk2(p1.x, p1.y);
            uu.u[3] = pk2(p1.z, p1.w);
            af[kc] = uu.s8;
        }
        ss += __shfl_xor(ss, 16, 64);   // lanes {l15,+16,+32,+48} share a row
        ss += __shfl_xor(ss, 32, 64);
        sc = 1.0f / fmaxf(sqrtf(ss), 1e-12f);
    }

    // ---- (6) labels: one-hot dot with index over this lane's quarter-row ----
    int lab_all;
    {
        float a0 = 0.f, a1 = 0.f;
        #pragma unroll
        for (int i = 0; i < 8; i += 2) {
            float4 t0 = traw[i];
            float4 t1 = traw[i + 1];
            float c0 = (float)(quad * 32 + i * 4);
            a0 = fmaf(t0.x, c0,       a0); a0 = fmaf(t0.y, c0 + 1.f, a0);
            a0 = fmaf(t0.z, c0 + 2.f, a0); a0 = fmaf(t0.w, c0 + 3.f, a0);
            a1 = fmaf(t1.x, c0 + 4.f, a1); a1 = fmaf(t1.y, c0 + 5.f, a1);
            a1 = fmaf(t1.z, c0 + 6.f, a1); a1 = fmaf(t1.w, c0 + 7.f, a1);
        }
        float lf = a0 + a1;
        lf += __shfl_xor(lf, 16, 64);   // combine the 4 quarters of row l15
        lf += __shfl_xor(lf, 32, 64);
        lab_all = (int)(lf + 0.5f);     // lane L holds label of row (L&15)
    }

    __syncthreads();

    // ---- MFMA: 16 rows x 128 classes ----
    f32x4 acc[8];
    #pragma unroll
    for (int tc = 0; tc < 8; ++tc) acc[tc] = (f32x4){0.f, 0.f, 0.f, 0.f};
    #pragma unroll 2
    for (int tc = 0; tc < 8; ++tc) {
        short8 b[4];
        #pragma unroll
        for (int kc = 0; kc < 4; ++kc)
            b[kc] = *(const short8*)(sw + (tc * 16 + l15) * PITCH + kc * 32 + quad * 8);
        #pragma unroll
        for (int kc = 0; kc < 4; ++kc)
            acc[tc] = __builtin_amdgcn_mfma_f32_16x16x32_bf16(af[kc], b[kc], acc[tc], 0, 0, 0);
    }

    // ---- Epilogue (R6-proven): fixed C0, label column excluded from the sum ----
    float lsum = 0.0f;
    {
        float se[4];
        #pragma unroll
        for (int v = 0; v < 4; ++v) {
            const int rl  = quad * 4 + v;              // C/D: row = quad*4+reg
            const int lab = __shfl(lab_all, rl, 64);
            const float scv = __shfl(sc, rl, 64);
            const bool own  = (l15 == (lab & 15));
            const int  tcl  = lab >> 4;
            const float k1  = S_ * scv;
            float s = 1e-38f, craw = 0.f;
            #pragma unroll
            for (int tc = 0; tc < 8; ++tc) {
                float av = acc[tc][v];
                const bool isl = own && (tc == tcl);
                s += isl ? 0.f : __expf(fmaf(k1, av, -C0_));
                craw = isl ? av : craw;
            }
            float cl = craw * scv;
            float s2 = fmaxf(1.0f - cl * cl, 0.0f);
            float ph = cl * COSM_ - sqrtf(s2) * SINM_;
            ph = (cl > TH_) ? ph : (cl - MM_);
            s += own ? __expf(fmaf(S_, ph, -C0_)) : 0.f;
            lsum -= own ? S_ * ph : 0.f;
            se[v] = s;
        }
        #pragma unroll
        for (int m = 1; m < 16; m <<= 1) {             // batched: 4 indep shuffles/round
            #pragma unroll
            for (int v = 0; v < 4; ++v) se[v] += __shfl_xor(se[v], m, 64);
        }
        if (l15 == 0) {
            #pragma unroll
            for (int v = 0; v < 4; ++v) lsum += __logf(se[v]) + C0_;
        }
    }

    // ---- Wave + block reduction, one atomic per block ----
    #pragma unroll
    for (int m = 1; m < 64; m <<= 1) lsum += __shfl_xor(lsum, m, 64);
    if (lane == 0) swsum[wv] = lsum;
    __syncthreads();
    if (t == 0) {
        float tot = swsum[0] + swsum[1] + swsum[2] + swsum[3];
        atomicAdd(out, tot * (1.0f / (float)NB));
    }
}

extern "C" void kernel_launch(void* const* d_in, const int* in_sizes, int n_in,
                              void* d_out, int out_size, void* d_ws, size_t ws_size,
                              hipStream_t stream) {
    const float* predict = (const float*)d_in[0];
    const float* target  = (const float*)d_in[1];
    const float* weight  = (const float*)d_in[2];
    float* out = (float*)d_out;
    unsigned int* wn = (unsigned int*)d_ws;  // 128*64 uints = 32 KB bf16 wn

    wnorm_kernel<<<dim3(NC), dim3(64), 0, stream>>>(weight, wn, out);
    arcloss_kernel<<<dim3(NB / 64), dim3(256), 0, stream>>>(predict, target,
                                                            (const unsigned short*)wn, out);
}